// Round 4
// baseline (53.013 us; speedup 1.0000x reference)
//
#include <hip/hip_runtime.h>
#include <hip/hip_bf16.h>

// MyDeConv1D as GEMM: out[b,t,f] = sum_{j,c} x[b,t+28-4j,c]*W[c,j,f] + cnt(t)*256*bias[f]
// M=32768, N=256, K=2048, bf16 MFMA 16x16x32.
// R4: channel-chunked double-buffered LDS staging (overlaps x HBM fetch with MFMA),
//     pad-to-80B LDS rows (bank-group (5*row+q)%8 -> worst 2-way, free),
//     cs-outer / j-inner with 2-deep A/B register pipeline.

#define B_    16
#define T_    2048
#define C_    256
#define KT    8
#define F_    256
#define SH    28
#define BT    128
#define ROWS  (BT + SH)      // 156
#define CH    32             // channels per LDS chunk
#define LSTR  40             // ushorts per row = 80 B (64 data + 16 pad)
#define CHUNK (ROWS * LSTR)  // 6240 ushorts = 12480 B

typedef __attribute__((ext_vector_type(8))) short short8;
typedef __attribute__((ext_vector_type(4))) float floatx4;

// W[c][j][f] f32 -> Wf frag order fid=(cs*8+j)*16+g : lane holds
// B[k=q*8+i][n=l16] for f=g*16+l16, c=cs*32+q*8+i. 1KB/frag, chunk-contiguous.
__global__ __launch_bounds__(256) void wprep_kernel(const float* __restrict__ W,
                                                    ushort* __restrict__ Wf) {
    const int tid  = threadIdx.x;
    const int fid  = blockIdx.x * 4 + (tid >> 6);   // 0..1023
    const int lane = tid & 63;
    const int g    = fid & 15;
    const int j    = (fid >> 4) & 7;
    const int cs   = fid >> 7;
    const int c0   = cs * 32 + (lane >> 4) * 8;
    const int f    = g * 16 + (lane & 15);
    short8 pk;
    #pragma unroll
    for (int i = 0; i < 8; ++i) {
        __hip_bfloat16 h = __float2bfloat16(W[((c0 + i) * KT + j) * F_ + f]);
        pk[i] = *reinterpret_cast<const short*>(&h);
    }
    *reinterpret_cast<short8*>(Wf + fid * 512 + lane * 8) = pk;
}

__device__ inline short8 cvt8(float4 a, float4 b) {
    float v[8] = {a.x, a.y, a.z, a.w, b.x, b.y, b.z, b.w};
    short8 r;
    #pragma unroll
    for (int i = 0; i < 8; ++i) {
        __hip_bfloat16 h = __float2bfloat16(v[i]);
        r[i] = *reinterpret_cast<const short*>(&h);
    }
    return r;
}

__global__ __launch_bounds__(512, 2) void deconv_kernel(
        const float* __restrict__ x, const ushort* __restrict__ Wf,
        const float* __restrict__ bias, float* __restrict__ out) {
    __shared__ ushort xs[2 * CHUNK];                 // 24.96 KiB
    const int t0   = blockIdx.x * BT;
    const int b    = blockIdx.y;
    const int tid  = threadIdx.x;
    const int lane = tid & 63, wave = tid >> 6;      // wave owns f[w*32, w*32+32)
    const int l16  = lane & 15, q = lane >> 4;

    // staging tasks: idx in [0, ROWS*4), task = 8 channels of one row.
    const int r0  = tid >> 2,  qd0 = tid & 3;        // always valid (tid<512 -> r0<128<156)
    const int idx1 = tid + 512;
    const int r1  = idx1 >> 2, qd1 = idx1 & 3;       // valid iff idx1 < ROWS*4 (=624)

    float4 R[2][2];

#define STAGE_LOAD(cs_) do {                                                   \
        R[0][0] = make_float4(0,0,0,0); R[0][1] = make_float4(0,0,0,0);        \
        R[1][0] = make_float4(0,0,0,0); R[1][1] = make_float4(0,0,0,0);        \
        if (t0 + r0 < T_) {                                                    \
            const float4* p = reinterpret_cast<const float4*>(                 \
                x + ((size_t)(b * T_ + t0 + r0) * C_ + (cs_) * CH + qd0 * 8)); \
            R[0][0] = p[0]; R[0][1] = p[1];                                    \
        }                                                                      \
        if (idx1 < ROWS * 4 && t0 + r1 < T_) {                                 \
            const float4* p = reinterpret_cast<const float4*>(                 \
                x + ((size_t)(b * T_ + t0 + r1) * C_ + (cs_) * CH + qd1 * 8)); \
            R[1][0] = p[0]; R[1][1] = p[1];                                    \
        } } while (0)

#define STAGE_WRITE(buf_) do {                                                 \
        ushort* d_ = xs + (buf_) * CHUNK;                                      \
        *reinterpret_cast<short8*>(d_ + r0 * LSTR + qd0 * 8) =                 \
            cvt8(R[0][0], R[0][1]);                                            \
        if (idx1 < ROWS * 4)                                                   \
            *reinterpret_cast<short8*>(d_ + r1 * LSTR + qd1 * 8) =             \
                cvt8(R[1][0], R[1][1]);                                        \
        } while (0)

    float bf2[2];
    bf2[0] = bias[wave * 32 + l16];
    bf2[1] = bias[wave * 32 + 16 + l16];

    floatx4 acc[8][2];
    #pragma unroll
    for (int mf = 0; mf < 8; ++mf) {
        acc[mf][0] = (floatx4){0.f, 0.f, 0.f, 0.f};
        acc[mf][1] = (floatx4){0.f, 0.f, 0.f, 0.f};
    }

    const ushort* wb = Wf + (wave * 2) * 512 + lane * 8;  // + cs*65536 + j*8192 + nf*512

#define LOAD_A(buf_, j_, arr) do {                                             \
        const ushort* s_ = xs + (buf_) * CHUNK                                 \
                           + (l16 + (SH - 4 * (j_))) * LSTR + q * 8;           \
        _Pragma("unroll")                                                      \
        for (int mf = 0; mf < 8; ++mf)                                         \
            arr[mf] = *reinterpret_cast<const short8*>(s_ + mf * 16 * LSTR);   \
        } while (0)

#define LOAD_B(cs_, j_, arr) do {                                              \
        const ushort* p_ = wb + (size_t)(cs_) * 65536 + (j_) * 8192;           \
        arr[0] = *reinterpret_cast<const short8*>(p_);                         \
        arr[1] = *reinterpret_cast<const short8*>(p_ + 512);                   \
        } while (0)

#define DO_MFMA(aa, bb) do {                                                   \
        _Pragma("unroll")                                                      \
        for (int mf = 0; mf < 8; ++mf) {                                       \
            acc[mf][0] = __builtin_amdgcn_mfma_f32_16x16x32_bf16(              \
                aa[mf], bb[0], acc[mf][0], 0, 0, 0);                           \
            acc[mf][1] = __builtin_amdgcn_mfma_f32_16x16x32_bf16(              \
                aa[mf], bb[1], acc[mf][1], 0, 0, 0);                           \
        } } while (0)

    // prologue: stage chunk 0
    STAGE_LOAD(0);
    STAGE_WRITE(0);
    __syncthreads();

    for (int cs = 0; cs < 8; ++cs) {
        const int buf = cs & 1;
        if (cs < 7) STAGE_LOAD(cs + 1);            // x loads in flight under MFMA

        short8 a[2][8], bb[2][2];
        LOAD_A(buf, 0, a[0]); LOAD_B(cs, 0, bb[0]);
        LOAD_A(buf, 1, a[1]); LOAD_B(cs, 1, bb[1]);
        #pragma unroll
        for (int j = 0; j < 8; ++j) {
            DO_MFMA(a[j & 1], bb[j & 1]);
            if (j < 6) { LOAD_A(buf, j + 2, a[j & 1]); LOAD_B(cs, j + 2, bb[j & 1]); }
        }

        if (cs < 7) STAGE_WRITE(buf ^ 1);
        __syncthreads();
    }

    // epilogue: + cnt(t)*C*bias ; C/D map: col=l16, row=q*4+r
    #pragma unroll
    for (int nf = 0; nf < 2; ++nf) {
        const int f = wave * 32 + nf * 16 + l16;
        #pragma unroll
        for (int mf = 0; mf < 8; ++mf) {
            #pragma unroll
            for (int r = 0; r < 4; ++r) {
                const int t = t0 + mf * 16 + q * 4 + r;
                const int jmin = (t < T_ - SH) ? 0 : (((t - (T_ - SH)) >> 2) + 1);
                out[(b * T_ + t) * F_ + f] =
                    acc[mf][nf][r] + (float)(8 - jmin) * 256.0f * bf2[nf];
            }
        }
    }
#undef STAGE_LOAD
#undef STAGE_WRITE
#undef LOAD_A
#undef LOAD_B
#undef DO_MFMA
}

extern "C" void kernel_launch(void* const* d_in, const int* in_sizes, int n_in,
                              void* d_out, int out_size, void* d_ws, size_t ws_size,
                              hipStream_t stream) {
    const float* x    = (const float*)d_in[0];
    const float* W    = (const float*)d_in[1];   // (C,KT,F)
    const float* bias = (const float*)d_in[2];
    float* out = (float*)d_out;
    ushort* Wf = (ushort*)d_ws;                  // 1 MiB scratch

    wprep_kernel<<<256, 256, 0, stream>>>(W, Wf);
    dim3 grid(T_ / BT, B_);
    deconv_kernel<<<grid, 512, 0, stream>>>(x, Wf, bias, out);
}

// Round 5
// 45.231 us; speedup vs baseline: 1.1721x; 1.1721x over previous
//
#include <hip/hip_runtime.h>
#include <hip/hip_bf16.h>

// MyDeConv1D as GEMM: out[b,t,f] = sum_{j,c} x[b,t+28-4j,c]*W[c,j,f] + cnt(t)*256*bias[f]
// M=32768, N=256, K=2048, bf16 MFMA 16x16x32.
// R5: wave grid W_m=2 x W_f=4 (MF=4,NF=4) balances A-LDS (536MB) vs B-L2 (L1-paired);
//     LDS [156][128B] rows + verified (slot ^= row&7) swizzle (2-way = free);
//     4 chunks of 64 ch, ONE barrier/chunk, depth-2 A/B register rings, setprio
//     around MFMA clusters.

#define B_    16
#define T_    2048
#define C_    256
#define KT    8
#define F_    256
#define SH    28
#define BT    128
#define ROWS  (BT + SH)        // 156
#define NTASK (ROWS * 8)       // 1248 16B-slot staging tasks per chunk
#define CHW   (ROWS * 64)      // ushorts per chunk buffer (156 rows x 128B)

typedef __attribute__((ext_vector_type(8))) short short8;
typedef __attribute__((ext_vector_type(4))) float floatx4;

// Wf step-major: S = (cs*8 + j)*2 + kh in 0..63, g in 0..15.
// frag (S,g): lane(l16,q) holds B[k=q*8+i][f=g*16+l16], c = cs*64 + kh*32 + q*8 + i.
// 1KB per frag, fully coalesced producer and consumer.
__global__ __launch_bounds__(256) void wprep_kernel(const float* __restrict__ W,
                                                    ushort* __restrict__ Wf) {
    const int tid  = threadIdx.x;
    const int fid  = blockIdx.x * 4 + (tid >> 6);   // 0..1023
    const int lane = tid & 63;
    const int g    = fid & 15;
    const int S    = fid >> 4;
    const int kh   = S & 1, j = (S >> 1) & 7, cs = S >> 4;
    const int c0   = cs * 64 + kh * 32 + (lane >> 4) * 8;
    const int f    = g * 16 + (lane & 15);
    short8 pk;
    #pragma unroll
    for (int i = 0; i < 8; ++i) {
        __hip_bfloat16 h = __float2bfloat16(W[((c0 + i) * KT + j) * F_ + f]);
        pk[i] = *reinterpret_cast<const short*>(&h);
    }
    *reinterpret_cast<short8*>(Wf + (size_t)fid * 512 + lane * 8) = pk;
}

__device__ inline short8 cvt8(float4 a, float4 b) {
    float v[8] = {a.x, a.y, a.z, a.w, b.x, b.y, b.z, b.w};
    short8 r;
    #pragma unroll
    for (int i = 0; i < 8; ++i) {
        __hip_bfloat16 h = __float2bfloat16(v[i]);
        r[i] = *reinterpret_cast<const short*>(&h);
    }
    return r;
}

__global__ __launch_bounds__(512, 2) void deconv_kernel(
        const float* __restrict__ x, const ushort* __restrict__ Wf,
        const float* __restrict__ bias, float* __restrict__ out) {
    __shared__ ushort xs[2 * CHW];                  // 39 KiB
    const int t0   = blockIdx.x * BT;
    const int b    = blockIdx.y;
    const int tid  = threadIdx.x;
    const int lane = tid & 63, w = tid >> 6;
    const int wf   = w & 3, wm = w >> 2;            // wave = (wm: row-half, wf: f-quarter)
    const int l16  = lane & 15, q = lane >> 4;

    // staging tasks: u -> row=u>>3 (16B slot g=u&7 = 8 channels). 3 rounds.
    const int r0 = tid >> 3,          g0 = tid & 7;            // rows 0..63   (always valid)
    const int r1 = (tid + 512) >> 3,  g1 = tid & 7;            // rows 64..127 (always valid)
    const int r2 = (tid + 1024) >> 3, g2 = tid & 7;            // rows 128..155 (tid<224)

    float4 A0, B0, A1, B1, A2, B2;

#define STAGE_LOAD(cs_) do {                                                   \
        const float4 z_ = make_float4(0.f, 0.f, 0.f, 0.f);                     \
        A0 = z_; B0 = z_; A1 = z_; B1 = z_; A2 = z_; B2 = z_;                  \
        {   const float4* p_ = reinterpret_cast<const float4*>(                \
                x + ((size_t)(b * T_ + t0 + r0) * C_ + (cs_) * 64 + g0 * 8));  \
            A0 = p_[0]; B0 = p_[1]; }                                          \
        {   const float4* p_ = reinterpret_cast<const float4*>(                \
                x + ((size_t)(b * T_ + t0 + r1) * C_ + (cs_) * 64 + g1 * 8));  \
            A1 = p_[0]; B1 = p_[1]; }                                          \
        if (tid < 224 && t0 + r2 < T_) {                                       \
            const float4* p_ = reinterpret_cast<const float4*>(                \
                x + ((size_t)(b * T_ + t0 + r2) * C_ + (cs_) * 64 + g2 * 8));  \
            A2 = p_[0]; B2 = p_[1]; } } while (0)

#define STAGE_WRITE(buf_) do {                                                 \
        ushort* d_ = xs + (buf_) * CHW;                                        \
        *reinterpret_cast<short8*>(d_ + r0 * 64 + ((g0 ^ (r0 & 7)) * 8)) =     \
            cvt8(A0, B0);                                                      \
        *reinterpret_cast<short8*>(d_ + r1 * 64 + ((g1 ^ (r1 & 7)) * 8)) =     \
            cvt8(A1, B1);                                                      \
        if (tid < 224)                                                         \
            *reinterpret_cast<short8*>(d_ + r2 * 64 + ((g2 ^ (r2 & 7)) * 8)) = \
                cvt8(A2, B2);                                                  \
        } while (0)

    // A frag (step s=j*2+kh, frag mf): row = SH-4j + wm*64 + mf*16 + l16,
    // logical slot kh*4+q, physical = logical ^ (row&7).
#define LOAD_A(buf_, s_, arr) do {                                             \
        const int j_ = (s_) >> 1, kh_ = (s_) & 1;                              \
        const int rb_ = SH - 4 * j_ + wm * 64 + l16;                           \
        _Pragma("unroll")                                                      \
        for (int mf = 0; mf < 4; ++mf) {                                       \
            const int row_ = rb_ + mf * 16;                                    \
            arr[mf] = *reinterpret_cast<const short8*>(                        \
                xs + (buf_) * CHW + row_ * 64 +                                \
                (((kh_ * 4 + q) ^ (row_ & 7)) * 8));                           \
        } } while (0)

#define LOAD_B(S_, arr) do {                                                   \
        const ushort* p_ = wbase + (size_t)(S_) * 8192;                        \
        _Pragma("unroll")                                                      \
        for (int nf = 0; nf < 4; ++nf)                                         \
            arr[nf] = *reinterpret_cast<const short8*>(p_ + nf * 512);         \
        } while (0)

#define DO_MFMA(aa, bb) do {                                                   \
        _Pragma("unroll")                                                      \
        for (int mf = 0; mf < 4; ++mf)                                         \
            _Pragma("unroll")                                                  \
            for (int nf = 0; nf < 4; ++nf)                                     \
                acc[mf][nf] = __builtin_amdgcn_mfma_f32_16x16x32_bf16(         \
                    aa[mf], bb[nf], acc[mf][nf], 0, 0, 0);                     \
        } while (0)

    const ushort* wbase = Wf + wf * 2048 + (size_t)lane * 8;

    float bf4[4];
    #pragma unroll
    for (int nf = 0; nf < 4; ++nf) bf4[nf] = bias[wf * 64 + nf * 16 + l16];

    floatx4 acc[4][4];
    #pragma unroll
    for (int mf = 0; mf < 4; ++mf)
        #pragma unroll
        for (int nf = 0; nf < 4; ++nf)
            acc[mf][nf] = (floatx4){0.f, 0.f, 0.f, 0.f};

    short8 aA[4], aB[4], bA[4], bB[4];

    // prologue: stage chunk 0, prime B ring
    STAGE_LOAD(0);
    LOAD_B(0, bA);
    LOAD_B(1, bB);
    STAGE_WRITE(0);
    __syncthreads();

    for (int cs = 0; cs < 4; ++cs) {
        const int buf = cs & 1;
        if (cs < 3) STAGE_LOAD(cs + 1);          // next chunk's x loads in flight
        LOAD_A(buf, 0, aA);
        LOAD_A(buf, 1, aB);
        #pragma unroll
        for (int s = 0; s < 16; s += 2) {
            const int S = cs * 16 + s;
            __builtin_amdgcn_s_setprio(1);
            DO_MFMA(aA, bA);
            __builtin_amdgcn_s_setprio(0);
            if (s < 14) LOAD_A(buf, s + 2, aA);
            LOAD_B((S + 2) & 63, bA);
            __builtin_amdgcn_s_setprio(1);
            DO_MFMA(aB, bB);
            __builtin_amdgcn_s_setprio(0);
            if (s < 14) LOAD_A(buf, s + 3, aB);
            LOAD_B((S + 3) & 63, bB);
        }
        if (cs < 3) STAGE_WRITE(buf ^ 1);
        __syncthreads();
    }

    // epilogue: + cnt(t)*256*bias; C/D map col=l16 (f), row=q*4+r
    #pragma unroll
    for (int mf = 0; mf < 4; ++mf) {
        #pragma unroll
        for (int nf = 0; nf < 4; ++nf) {
            const int f = wf * 64 + nf * 16 + l16;
            #pragma unroll
            for (int r = 0; r < 4; ++r) {
                const int t = t0 + wm * 64 + mf * 16 + q * 4 + r;
                const int jmin = (t < T_ - SH) ? 0 : (((t - (T_ - SH)) >> 2) + 1);
                out[(size_t)(b * T_ + t) * F_ + f] =
                    acc[mf][nf][r] + (float)(8 - jmin) * 256.0f * bf4[nf];
            }
        }
    }
#undef STAGE_LOAD
#undef STAGE_WRITE
#undef LOAD_A
#undef LOAD_B
#undef DO_MFMA
}

extern "C" void kernel_launch(void* const* d_in, const int* in_sizes, int n_in,
                              void* d_out, int out_size, void* d_ws, size_t ws_size,
                              hipStream_t stream) {
    const float* x    = (const float*)d_in[0];
    const float* W    = (const float*)d_in[1];   // (C,KT,F)
    const float* bias = (const float*)d_in[2];
    float* out = (float*)d_out;
    ushort* Wf = (ushort*)d_ws;                  // 1 MiB scratch

    wprep_kernel<<<256, 256, 0, stream>>>(W, Wf);
    dim3 grid(T_ / BT, B_);
    deconv_kernel<<<grid, 512, 0, stream>>>(x, Wf, bias, out);
}